// Round 3
// baseline (692.577 us; speedup 1.0000x reference)
//
#include <hip/hip_runtime.h>
#include <math.h>

// DCT2net fused kernel, R3: single-barrier software-pipelined row loop.
//   t[ki,kj]  = sum_{x,y} c1[x][ki] c1[y][kj] X[h0+x, w0+y]   (separable DCT)
//   nz = shrink(t/(3s));  w = 1/(1+sum nz);  yw = w * t * nz
//   z[dx,dy]  = sum_{ki,kj} c1[dx][ki] c1[dy][kj] yw           (inverse = same c1)
//   out[a,b]  = fold(z) / boxsum13(w)
//
// Pipeline at iteration r (one __syncthreads per r):
//   A: stage input row r+1 -> xrow[(r+1)&1], prefetch row r+2
//   B: hDCT of row r -> shift into Rv ring (rows r-12..r)
//   D: w for patch row r-13 from red[(r-1)&1]; fold prev nzt (scaled) into Hreg
//   E: retire fold row r-25 -> Hrow[r&1]; shift Hreg
//   F: synth partials for row r-26 from Hrow[(r-1)&1] -> red2[r&1]
//   G: (wave 12) output row r-27 = sum red2[(r-1)&1] / divisor(wring rows r-27..r-15)
//   C: vDCT patch row r-12 (even/odd sym), shrink -> new nzt, red[r&1]=pnz
// All cross-wave LDS is parity double-buffered; one-iteration delay rides the
// single barrier. wring has 16 slots (rows r-28..r-13 live, rows r-27..r-15 read).

#define P13   13
#define IMGW  512
#define OUTW  488
#define WC    52
#define PWN   64
#define NJ    13
#define SEGH  19
#define NSEG  26            // 26*19 = 494 >= 488
#define NWCH  10
#define NTHREADS (PWN * NJ) // 832
#define XROWN 80

struct C1mat { float v[P13 * P13]; };  // v[x*13+k] = sqrt(2/13)*Ci[k]*cos((2x+1)k*pi/26)

__global__ __launch_bounds__(NTHREADS) void dct2net_fused(
    const float* __restrict__ xg,
    const float* __restrict__ sigmag,
    float* __restrict__ outg,
    C1mat c1)
{
    __shared__ float xrow[2][XROWN];     // staged input rows, parity ring
    __shared__ float red[2][NJ][PWN];    // pnz partials (parity)
    __shared__ float red2[2][NJ][PWN];   // synthesis partials (parity)
    __shared__ float Hrow[2][NJ][PWN];   // retired fold rows (parity)
    __shared__ float wring[16][PWN];     // per-patch-row weights, ring by ph & 15
    __shared__ float Hwrow[PWN];         // wave-12 divisor scratch (same-wave in-order)

    const int tid  = threadIdx.x;
    const int lane = tid & 63;
    const int ju   = __builtin_amdgcn_readfirstlane(tid >> 6);
    const int n    = blockIdx.z;
    const int ows  = blockIdx.x * WC;
    const int ohs  = blockIdx.y * SEGH;
    const int ohe  = (ohs + SEGH < OUTW) ? (ohs + SEGH) : OUTW;

    const float inv3s = 1.0f / (3.0f * sigmag[0]);
    const float* xin  = xg + (size_t)n * IMGW * IMGW;

    float Rv[P13], Hreg[P13], nzt[P13];
#pragma unroll
    for (int k = 0; k < P13; ++k) { Rv[k] = 0.0f; Hreg[k] = 0.0f; nzt[k] = 0.0f; }

    const bool stager = (tid < PWN + P13 - 1);   // 76 loader threads (waves 0-1)
    int colc = ows + tid; colc = (colc < IMGW) ? colc : (IMGW - 1);
    float pre = 0.0f;
    if (stager) {
        xrow[ohs & 1][tid] = xin[(size_t)ohs * IMGW + colc];          // row ohs
        int r1 = ohs + 1; r1 = (r1 < IMGW) ? r1 : (IMGW - 1);
        pre = xin[(size_t)r1 * IMGW + colc];                          // row ohs+1
    }

    const int rend = ohs + SEGH + 26;            // last iter outputs row ohs+SEGH-1

    for (int r = ohs; r <= rend; ++r) {
        __syncthreads();                          // the one barrier
        const int par  = r & 1;
        const int parN = par ^ 1;

        // --- A: stage row r+1, prefetch row r+2
        if (stager) {
            xrow[parN][tid] = pre;
            int pr = r + 2; pr = (pr < IMGW) ? pr : (IMGW - 1);
            pre = xin[(size_t)pr * IMGW + colc];
        }

        // --- B: horizontal DCT of row r -> Rv ring (Rv[x] = row r-12+x)
        {
            float acc = 0.0f;
#pragma unroll
            for (int y = 0; y < P13; ++y) acc += c1.v[y * P13 + ju] * xrow[par][lane + y];
#pragma unroll
            for (int k = 0; k < P13 - 1; ++k) Rv[k] = Rv[k + 1];
            Rv[P13 - 1] = acc;
        }

        // --- D: weight for patch row ph1 = r-13; fold prev nzt into Hreg
        {
            float snz = 0.0f;
#pragma unroll
            for (int jj = 0; jj < NJ; ++jj) snz += red[parN][jj][lane];
            const float w1 = __builtin_amdgcn_rcpf(1.0f + snz);
            if (ju == NJ - 1) wring[(r - 13) & 15][lane] = w1;
#pragma unroll
            for (int i = 0; i < P13; ++i) nzt[i] *= w1;
#pragma unroll
            for (int dx = 0; dx < 6; ++dx) {
                float E = c1.v[dx * P13 + 0] * nzt[0];
#pragma unroll
                for (int i = 2; i < P13; i += 2) E += c1.v[dx * P13 + i] * nzt[i];
                float O = c1.v[dx * P13 + 1] * nzt[1];
#pragma unroll
                for (int i = 3; i < P13; i += 2) O += c1.v[dx * P13 + i] * nzt[i];
                Hreg[dx]      += E + O;
                Hreg[12 - dx] += E - O;
            }
            float z6 = c1.v[6 * P13 + 0] * nzt[0];
#pragma unroll
            for (int i = 2; i < P13; i += 2) z6 += c1.v[6 * P13 + i] * nzt[i];
            Hreg[6] += z6;
        }

        // --- E: retire fold row r-25 -> Hrow[par]; shift ring
        Hrow[par][ju][lane] = Hreg[0];
#pragma unroll
        for (int k = 0; k < P13 - 1; ++k) Hreg[k] = Hreg[k + 1];
        Hreg[P13 - 1] = 0.0f;

        // --- F: synthesis partial for row r-26 from Hrow[parN]
        {
            float part = 0.0f;
#pragma unroll
            for (int dy = 0; dy < P13; ++dy) {
                int lc = lane + 12 - dy; lc = (lc < PWN) ? lc : (PWN - 1);
                part += c1.v[dy * P13 + ju] * Hrow[parN][ju][lc];
            }
            red2[par][ju][lane] = part;
        }

        // --- G: wave 12 finalizes output row a3 = r-27
        if (ju == NJ - 1) {
            const int a3 = r - 27;
            if (a3 >= ohs) {
                float num = 0.0f;
#pragma unroll
                for (int jj = 0; jj < NJ; ++jj) num += red2[parN][jj][lane];
                float hw = 0.0f;
#pragma unroll
                for (int dx = 0; dx < P13; ++dx) hw += wring[(a3 + dx) & 15][lane];
                Hwrow[lane] = hw;                 // same-wave DS: in program order
                float den = 0.0f;
#pragma unroll
                for (int dy = 0; dy < P13; ++dy) {
                    int lc = lane + 12 - dy; lc = (lc < PWN) ? lc : (PWN - 1);
                    den += Hwrow[lc];
                }
                int ow = ows + lane;
                if (lane < WC && ow < OUTW && a3 < ohe)
                    outg[((size_t)n * OUTW + a3) * OUTW + ow] = num * __builtin_amdgcn_rcpf(den);
            }
        }

        // --- C: vertical DCT patch row r-12 (even/odd symmetry) + shrink -> new nzt
        {
            float Se[6], So[6];
#pragma unroll
            for (int k = 0; k < 6; ++k) { Se[k] = Rv[k] + Rv[12 - k]; So[k] = Rv[k] - Rv[12 - k]; }
            float pnz = 0.0f;
#pragma unroll
            for (int i = 0; i < P13; ++i) {
                float t;
                if ((i & 1) == 0) {
                    t = c1.v[6 * P13 + i] * Rv[6];
#pragma unroll
                    for (int k = 0; k < 6; ++k) t += c1.v[k * P13 + i] * Se[k];
                } else {
                    t = c1.v[0 * P13 + i] * So[0];
#pragma unroll
                    for (int k = 1; k < 6; ++k) t += c1.v[k * P13 + i] * So[k];
                }
                float u = t * inv3s;
                u = fminf(fmaxf(u, -1.3f), 1.3f);     // clamp: u^64 <= 2e7, nz err ~5e-8
                float p2 = u * u, p4 = p2 * p2, p8 = p4 * p4;
                float p16 = p8 * p8, p32 = p16 * p16, p64 = p32 * p32;
                float nz = p64 * __builtin_amdgcn_rcpf(p64 + 1.0f);
                pnz += nz;
                nzt[i] = t * nz;
            }
            red[par][ju][lane] = pnz;
        }
    }
}

extern "C" void kernel_launch(void* const* d_in, const int* in_sizes, int n_in,
                              void* d_out, int out_size, void* d_ws, size_t ws_size,
                              hipStream_t stream)
{
    const float* x     = (const float*)d_in[0];
    const float* sigma = (const float*)d_in[1];
    float* out = (float*)d_out;

    C1mat c1;
    const double PI = 3.14159265358979323846;
    for (int xx = 0; xx < 13; ++xx)
        for (int k = 0; k < 13; ++k) {
            double Ci = (k == 0) ? (1.0 / sqrt(2.0)) : 1.0;
            c1.v[xx * 13 + k] =
                (float)(sqrt(2.0 / 13.0) * Ci * cos((2 * xx + 1) * k * PI / 26.0));
        }

    dim3 grid(NWCH, NSEG, 2);   // 10 x 26 x 2 = 520 blocks
    dim3 block(NTHREADS);       // 832 = 64 patch-cols x 13 kj-waves
    dct2net_fused<<<grid, block, 0, stream>>>(x, sigma, out, c1);
}

// Round 4
// 430.565 us; speedup vs baseline: 1.6085x; 1.6085x over previous
//
#include <hip/hip_runtime.h>
#include <math.h>

// DCT2net fused kernel, R4: 8-wave blocks, 2 kj per wave, single-barrier pipeline.
//   t[ki,kj]  = sum_{x,y} c1[x][ki] c1[y][kj] X[h0+x, w0+y]   (separable DCT)
//   nz = shrink(t/(3s));  w = 1/(1+sum nz);  yw = w * t * nz
//   z[dx,dy]  = sum_{ki,kj} c1[dx][ki] c1[dy][kj] yw           (inverse = same c1)
//   out[a,b]  = fold(z) / boxsum13(w)
//
// Wave q in [0,8) owns kj = q, and kj = q+8 if q<5 (13 total). 64 lanes = patch cols.
// 512-thread blocks lift the compiler's VGPR ceiling to 256 (832-thread blocks cap
// at 128 and starved at 60 -> serialized LDS waits). Waves 5-6 stage input, wave 7
// does final output; all cross-wave LDS parity double-buffered, ONE barrier/iter.
//
// Schedule at iteration r:
//   A: stage row r+1 -> xrow[(r+1)&1]; prefetch row r+2
//   D: w for patch row r-13 from red[(r-1)&1]; scale tn (row r-13); fold into Hreg;
//      retire fold row r-25 -> Hrow[r&1]; shift Hreg; (w7) wring[(r-13)&15] = w
//   F: synth partials for row r-26 from Hrow[(r-1)&1] -> red2[r&1]
//   G: (w7) output row r-27 from red2[(r-1)&1] / divisor(wring rows r-27..r-15)
//   B: hDCT row r (13 shared LDS reads, 2 j) -> shift Rv0/Rv1
//   C: vDCT patch row r-12 (even/odd sym) + shrink -> tn0/tn1, red[r&1] = pnz

#define P13   13
#define IMGW  512
#define OUTW  488
#define WC    52
#define PWN   64
#define NW    8              // waves per block
#define SEGH  20
#define NSEG  25             // 25*20 = 500 >= 488
#define NWCH  10
#define NTHREADS (PWN * NW)  // 512
#define HROWW 76             // 64 + 12 zero pad (kills index clamps in synth)

struct C1mat { float v[P13 * P13]; };  // v[x*13+k] = sqrt(2/13)*Ci[k]*cos((2x+1)k*pi/26)

__device__ __forceinline__ void vdct_shrink(const float (&Rv)[P13], const C1mat& c1,
                                            int j, float inv3s,
                                            float (&tn)[P13], float& pnz)
{
    float Se[6], So[6];
#pragma unroll
    for (int k = 0; k < 6; ++k) { Se[k] = Rv[k] + Rv[12 - k]; So[k] = Rv[k] - Rv[12 - k]; }
#pragma unroll
    for (int i = 0; i < P13; ++i) {
        float t;
        if ((i & 1) == 0) {
            t = c1.v[6 * P13 + i] * Rv[6];
#pragma unroll
            for (int k = 0; k < 6; ++k) t += c1.v[k * P13 + i] * Se[k];
        } else {
            t = c1.v[0 * P13 + i] * So[0];
#pragma unroll
            for (int k = 1; k < 6; ++k) t += c1.v[k * P13 + i] * So[k];
        }
        float u = t * inv3s;
        u = fminf(fmaxf(u, -1.3f), 1.3f);       // clamp: u^64 <= 2e7, nz err ~5e-8
        float p2 = u * u, p4 = p2 * p2, p8 = p4 * p4;
        float p16 = p8 * p8, p32 = p16 * p16, p64 = p32 * p32;
        float nz = p64 * __builtin_amdgcn_rcpf(p64 + 1.0f);
        pnz += nz;
        tn[i] = t * nz;
    }
}

__device__ __forceinline__ void fold_vert(float (&tn)[P13], const C1mat& c1,
                                          float w1, float (&H)[P13])
{
#pragma unroll
    for (int i = 0; i < P13; ++i) tn[i] *= w1;
#pragma unroll
    for (int dx = 0; dx < 6; ++dx) {
        float E = c1.v[dx * P13 + 0] * tn[0];
#pragma unroll
        for (int i = 2; i < P13; i += 2) E += c1.v[dx * P13 + i] * tn[i];
        float O = c1.v[dx * P13 + 1] * tn[1];
#pragma unroll
        for (int i = 3; i < P13; i += 2) O += c1.v[dx * P13 + i] * tn[i];
        H[dx]      += E + O;
        H[12 - dx] += E - O;
    }
    float z6 = c1.v[6 * P13 + 0] * tn[0];
#pragma unroll
    for (int i = 2; i < P13; i += 2) z6 += c1.v[6 * P13 + i] * tn[i];
    H[6] += z6;
}

__global__ __launch_bounds__(NTHREADS) void dct2net_fused(
    const float* __restrict__ xg,
    const float* __restrict__ sigmag,
    float* __restrict__ outg,
    C1mat c1)
{
    __shared__ float xrow[2][80];            // staged input rows (76 used)
    __shared__ float red[2][NW][PWN];        // pnz partials per wave
    __shared__ float red2[2][P13][PWN];      // synth partials per kj
    __shared__ float Hrow[2][P13][HROWW];    // retired fold rows, zero-padded cols 64..75
    __shared__ float wring[16][PWN];         // per-patch-row weights (wave 7 only)
    __shared__ float Hwrow[88];              // wave-7 divisor scratch (76 used)

    const int tid  = threadIdx.x;
    const int lane = tid & 63;
    const int ju   = __builtin_amdgcn_readfirstlane(tid >> 6);   // wave id 0..7
    const int j0   = ju;
    const int j1   = ju + 8;
    const bool has2 = (ju < 5);
    const int n    = blockIdx.z;
    const int ows  = blockIdx.x * WC;
    const int ohs  = blockIdx.y * SEGH;
    const int ohe  = (ohs + SEGH < OUTW) ? (ohs + SEGH) : OUTW;

    const float inv3s = 1.0f / (3.0f * sigmag[0]);
    const float* xin  = xg + (size_t)n * IMGW * IMGW;

    float Rv0[P13], Rv1[P13], tn0[P13], tn1[P13], H0[P13], H1[P13];
#pragma unroll
    for (int k = 0; k < P13; ++k) {
        Rv0[k] = 0.0f; Rv1[k] = 0.0f; tn0[k] = 0.0f; tn1[k] = 0.0f;
        H0[k] = 0.0f; H1[k] = 0.0f;
    }

    // zero the Hrow pads (cols 64..75, both parities) and Hwrow tail, once
    if (tid < 2 * P13 * 12) {
        int p  = tid / (P13 * 12);
        int rm = tid % (P13 * 12);
        Hrow[p][rm / 12][64 + (rm % 12)] = 0.0f;
    }
    if (tid >= 448 && tid < 448 + 24) Hwrow[64 + (tid - 448)] = 0.0f;

    // stagers: waves 5-6, threads [320, 396)
    const int sidx  = tid - 5 * PWN;
    const bool stager = (sidx >= 0) && (sidx < PWN + P13 - 1);
    int colc = ows + (stager ? sidx : 0);
    colc = (colc < IMGW) ? colc : (IMGW - 1);
    float pre = 0.0f;
    if (stager) {
        xrow[ohs & 1][sidx] = xin[(size_t)ohs * IMGW + colc];
        int r1 = ohs + 1; r1 = (r1 < IMGW) ? r1 : (IMGW - 1);
        pre = xin[(size_t)r1 * IMGW + colc];
    }

    const int rend = ohe + 26;   // last iter outputs row ohe-1

    for (int r = ohs; r <= rend; ++r) {
        __syncthreads();                       // the one barrier
        const int par  = r & 1;
        const int parN = par ^ 1;

        // --- A: stage row r+1, prefetch row r+2
        if (stager) {
            xrow[parN][sidx] = pre;
            int pr = r + 2; pr = (pr < IMGW) ? pr : (IMGW - 1);
            pre = xin[(size_t)pr * IMGW + colc];
        }

        // --- D: weight for patch row r-13; scale + fold previous tn into Hreg
        {
            float snz = 0.0f;
#pragma unroll
            for (int q = 0; q < NW; ++q) snz += red[parN][q][lane];
            const float w1 = __builtin_amdgcn_rcpf(1.0f + snz);
            if (ju == 7) wring[(r - 13) & 15][lane] = w1;
            fold_vert(tn0, c1, w1, H0);
            if (has2) fold_vert(tn1, c1, w1, H1);
            // retire fold row r-25
            Hrow[par][j0][lane] = H0[0];
            if (has2) Hrow[par][j1][lane] = H1[0];
#pragma unroll
            for (int k = 0; k < P13 - 1; ++k) { H0[k] = H0[k + 1]; H1[k] = H1[k + 1]; }
            H0[P13 - 1] = 0.0f; H1[P13 - 1] = 0.0f;
        }

        // --- F: synthesis partials for row r-26 from Hrow[parN]
        {
            float part0 = 0.0f;
#pragma unroll
            for (int dy = 0; dy < P13; ++dy)
                part0 += c1.v[dy * P13 + j0] * Hrow[parN][j0][lane + 12 - dy];
            red2[par][j0][lane] = part0;
            if (has2) {
                float part1 = 0.0f;
#pragma unroll
                for (int dy = 0; dy < P13; ++dy)
                    part1 += c1.v[dy * P13 + j1] * Hrow[parN][j1][lane + 12 - dy];
                red2[par][j1][lane] = part1;
            }
        }

        // --- G: wave 7 finalizes output row a3 = r-27
        if (ju == 7) {
            const int a3 = r - 27;
            if (a3 >= ohs) {
                float num = 0.0f;
#pragma unroll
                for (int jj = 0; jj < P13; ++jj) num += red2[parN][jj][lane];
                float hw = 0.0f;
#pragma unroll
                for (int dx = 0; dx < P13; ++dx) hw += wring[(a3 + dx) & 15][lane];
                Hwrow[lane] = hw;              // same-wave DS ops: in program order
                float den = 0.0f;
#pragma unroll
                for (int dy = 0; dy < P13; ++dy) den += Hwrow[lane + 12 - dy];
                int ow = ows + lane;
                if (lane < WC && ow < OUTW && a3 < ohe)
                    outg[((size_t)n * OUTW + a3) * OUTW + ow] = num * __builtin_amdgcn_rcpf(den);
            }
        }

        // --- B: horizontal DCT of row r (shared reads) -> Rv rings
        {
            float xw[P13];
#pragma unroll
            for (int y = 0; y < P13; ++y) xw[y] = xrow[par][lane + y];
            float acc0 = 0.0f, acc1 = 0.0f;
#pragma unroll
            for (int y = 0; y < P13; ++y) acc0 += c1.v[y * P13 + j0] * xw[y];
#pragma unroll
            for (int y = 0; y < P13; ++y) acc1 += c1.v[y * P13 + j1] * xw[y];
#pragma unroll
            for (int k = 0; k < P13 - 1; ++k) { Rv0[k] = Rv0[k + 1]; Rv1[k] = Rv1[k + 1]; }
            Rv0[P13 - 1] = acc0; Rv1[P13 - 1] = acc1;
        }

        // --- C: vertical DCT patch row r-12 + shrink -> new tn, publish pnz
        if (r >= ohs + 12) {
            float pnz = 0.0f;
            vdct_shrink(Rv0, c1, j0, inv3s, tn0, pnz);
            if (has2) vdct_shrink(Rv1, c1, j1, inv3s, tn1, pnz);
            red[par][ju][lane] = pnz;
        }
    }
}

extern "C" void kernel_launch(void* const* d_in, const int* in_sizes, int n_in,
                              void* d_out, int out_size, void* d_ws, size_t ws_size,
                              hipStream_t stream)
{
    const float* x     = (const float*)d_in[0];
    const float* sigma = (const float*)d_in[1];
    float* out = (float*)d_out;

    C1mat c1;
    const double PI = 3.14159265358979323846;
    for (int xx = 0; xx < 13; ++xx)
        for (int k = 0; k < 13; ++k) {
            double Ci = (k == 0) ? (1.0 / sqrt(2.0)) : 1.0;
            c1.v[xx * 13 + k] =
                (float)(sqrt(2.0 / 13.0) * Ci * cos((2 * xx + 1) * k * PI / 26.0));
        }

    dim3 grid(NWCH, NSEG, 2);   // 10 x 25 x 2 = 500 blocks
    dim3 block(NTHREADS);       // 512 = 64 patch-cols x 8 waves
    dct2net_fused<<<grid, block, 0, stream>>>(x, sigma, out, c1);
}

// Round 5
// 218.137 us; speedup vs baseline: 3.1750x; 1.9738x over previous
//
#include <hip/hip_runtime.h>
#include <math.h>

// DCT2net, R5: two kernels, lane = (col, kj) coordinate, barrier-free main loop.
//
// K2 (dct2net_k2): per lane-group of 16 (13 kj used), one patch column.
//   Streams image rows down a 61-output-row segment:
//     hDCT (x via ds_bpermute from 16 loader lanes) -> 13-reg ring Rv
//     vDCT + shrink (even/odd symmetry) -> tn[13], pnz
//     w = 1/(1+sum nz) via 4-step __shfl_xor butterfly within the 16-group
//     vertical inverse-DCT fold (scaled by w) -> 13-reg ring Hr
//     retire H row -> global Hg[img][a][col][16], w -> Wg[img][row][col]
//   NO __syncthreads in the loop; no cross-wave traffic at all.
// K3 (dct2net_k3): per out row: U[c][dy] = sum_j c1[dy][j] H[a][c][j] (169 FMA),
//   out = sum_dy U[b+12-dy][dy] / (13x13 box-sum of w). Same-wave LDS only.
//
// ws layout: Hg = 2*488*512*16 f32 (31.98 MB), Wg = 2*512*512 f32 (2 MB). ~34 MB.

#define P13    13
#define IMGW   512
#define OUTW   488
#define SEGH   61      // H rows per K2 segment; 8*61 = 488 exact
#define NSEG   8
#define HCOLS  512     // padded col dim of Hg
#define HPITCH 16      // padded j dim of Hg

struct C1mat { float v[P13 * P13]; };  // v[x*13+k] = sqrt(2/13)*Ci[k]*cos((2x+1)k*pi/26)

__device__ __forceinline__ void vdct_shrink(const float (&Rv)[P13], const C1mat& c1,
                                            float inv3s, float (&tn)[P13], float& pnz)
{
    float Se[6], So[6];
#pragma unroll
    for (int k = 0; k < 6; ++k) { Se[k] = Rv[k] + Rv[12 - k]; So[k] = Rv[k] - Rv[12 - k]; }
#pragma unroll
    for (int i = 0; i < P13; ++i) {
        float t;
        if ((i & 1) == 0) {
            t = c1.v[6 * P13 + i] * Rv[6];
#pragma unroll
            for (int k = 0; k < 6; ++k) t = fmaf(c1.v[k * P13 + i], Se[k], t);
        } else {
            t = c1.v[0 * P13 + i] * So[0];
#pragma unroll
            for (int k = 1; k < 6; ++k) t = fmaf(c1.v[k * P13 + i], So[k], t);
        }
        float u = t * inv3s;
        u = __builtin_amdgcn_fmed3f(u, -1.3f, 1.3f);   // clamp: u^64 <= 2e7, nz err ~5e-8
        float p2 = u * u, p4 = p2 * p2, p8 = p4 * p4;
        float p16 = p8 * p8, p32 = p16 * p16, p64 = p32 * p32;
        float nz = p64 * __builtin_amdgcn_rcpf(p64 + 1.0f);
        pnz += nz;
        tn[i] = t * nz;
    }
}

__device__ __forceinline__ void fold_vert(float (&tn)[P13], const C1mat& c1,
                                          float w1, float (&H)[P13])
{
#pragma unroll
    for (int i = 0; i < P13; ++i) tn[i] *= w1;
#pragma unroll
    for (int dx = 0; dx < 6; ++dx) {
        float E = c1.v[dx * P13 + 0] * tn[0];
#pragma unroll
        for (int i = 2; i < P13; i += 2) E = fmaf(c1.v[dx * P13 + i], tn[i], E);
        float O = c1.v[dx * P13 + 1] * tn[1];
#pragma unroll
        for (int i = 3; i < P13; i += 2) O = fmaf(c1.v[dx * P13 + i], tn[i], O);
        H[dx]      += E + O;
        H[12 - dx] += E - O;
    }
    float z6 = c1.v[6 * P13 + 0] * tn[0];
#pragma unroll
    for (int i = 2; i < P13; i += 2) z6 = fmaf(c1.v[6 * P13 + i], tn[i], z6);
    H[6] += z6;
}

__global__ __launch_bounds__(256) void dct2net_k2(
    const float* __restrict__ xg, const float* __restrict__ sigmag,
    float* __restrict__ Hg, float* __restrict__ Wg, C1mat c1)
{
    __shared__ float c1lds[169];
    const int tid = threadIdx.x;
    if (tid < 169) c1lds[tid] = c1.v[tid];
    __syncthreads();                       // once, for the c1 table only

    const int lane = tid & 63;
    const int wv   = tid >> 6;             // wave 0..3
    const int g    = lane >> 4;            // col group 0..3 within wave
    const int jj   = lane & 15;            // kj (0..12 used, 13..15 idle)
    const int img  = blockIdx.z;
    const int hs   = blockIdx.y * SEGH;    // first H row of this segment
    const int cbw  = blockIdx.x * 16 + wv * 4;   // wave's first col
    const int col  = cbw + g;              // this lane's patch column (0..511)

    const float inv3s = 1.0f / (3.0f * sigmag[0]);
    const float* xin  = xg + (size_t)img * IMGW * IMGW;

    // per-lane c1 column for the hDCT (j = jj), from the LDS table
    float c1col[P13];
    {
        const int jc = (jj < 13) ? jj : 12;
#pragma unroll
        for (int y = 0; y < P13; ++y) c1col[y] = c1lds[y * P13 + jc];
    }

    float Rv[P13], Hr[P13];
#pragma unroll
    for (int k = 0; k < P13; ++k) { Rv[k] = 0.0f; Hr[k] = 0.0f; }

    int xcol = cbw + lane; xcol = (xcol < IMGW - 1) ? xcol : (IMGW - 1);
    float xv = 0.0f;
    if (lane < 16) xv = xin[(size_t)hs * IMGW + xcol];   // row hs, cols cbw..cbw+15

    // steps k=0..84: load/hDCT row hs+k; k>=12: patch row hs+k-12; k>=24: H row hs+k-24
    for (int k = 0; k <= 84; ++k) {
        // gather this wave's 16 staged x values via bpermute (sliding 13-window)
        float xw[P13];
#pragma unroll
        for (int y = 0; y < P13; ++y)
            xw[y] = __int_as_float(
                __builtin_amdgcn_ds_bpermute(4 * (g + y), __float_as_int(xv)));
        {   // prefetch next row (consumed next iteration -> latency hidden)
            int nr = hs + k + 1; nr = (nr < IMGW) ? nr : (IMGW - 1);
            if (lane < 16) xv = xin[(size_t)nr * IMGW + xcol];
        }
        // hDCT: two partial FMA chains
        float a0 = c1col[0] * xw[0], a1 = c1col[1] * xw[1];
#pragma unroll
        for (int y = 2; y < P13; y += 2) a0 = fmaf(c1col[y], xw[y], a0);
#pragma unroll
        for (int y = 3; y < P13; y += 2) a1 = fmaf(c1col[y], xw[y], a1);
#pragma unroll
        for (int q = 0; q < P13 - 1; ++q) Rv[q] = Rv[q + 1];
        Rv[P13 - 1] = a0 + a1;

        if (k >= 12) {
            const int ph = hs + k - 12;    // patch row (<= 499 by construction)
            float tn[P13]; float pnz = 0.0f;
            vdct_shrink(Rv, c1, inv3s, tn, pnz);
            if (jj >= 13) pnz = 0.0f;      // idle lanes contribute 0
            // 16-lane butterfly: every lane of the group gets sum of 13 pnz
            pnz += __shfl_xor(pnz, 1, 16);
            pnz += __shfl_xor(pnz, 2, 16);
            pnz += __shfl_xor(pnz, 4, 16);
            pnz += __shfl_xor(pnz, 8, 16);
            const float w = __builtin_amdgcn_rcpf(1.0f + pnz);
            if (jj == 0) Wg[((size_t)img * IMGW + ph) * IMGW + col] = w;
            fold_vert(tn, c1, w, Hr);
            if (k >= 24) {                 // H row a complete (folds from rows a..a+12)
                const int a = hs + k - 24;
                Hg[(((size_t)img * OUTW + a) * HCOLS + col) * HPITCH + jj] = Hr[0];
            }
#pragma unroll
            for (int q = 0; q < P13 - 1; ++q) Hr[q] = Hr[q + 1];
            Hr[P13 - 1] = 0.0f;
        }
    }
}

__global__ __launch_bounds__(256) void dct2net_k3(
    const float* __restrict__ Hg, const float* __restrict__ Wg,
    float* __restrict__ outg, C1mat c1)
{
    __shared__ float U[4][76][14];   // stride 14: 2-way bank alias only (free)
    __shared__ float vw[4][80];
    const int tid  = threadIdx.x;
    const int lane = tid & 63;
    const int wv   = tid >> 6;
    const int img  = blockIdx.z;
    const int a    = blockIdx.y * 4 + wv;      // out row (<= 487)
    const int cb   = blockIdx.x * 64;          // out col base

    // build U[c][dy] and vw[c] for c in [cb, cb+76): 64 lanes + 12-lane halo pass
#pragma unroll
    for (int h = 0; h < 2; ++h) {
        const int li = lane + 64 * h;
        if (h == 0 || lane < 12) {
            int c = cb + li; c = (c < 499) ? c : 499;   // clamp; clamped slots unused
            const float* hp = &Hg[(((size_t)img * OUTW + a) * HCOLS + c) * HPITCH];
            float hv[P13];
            *(float4*)&hv[0] = *(const float4*)hp;
            *(float4*)&hv[4] = *(const float4*)(hp + 4);
            *(float4*)&hv[8] = *(const float4*)(hp + 8);
            hv[12] = hp[12];
#pragma unroll
            for (int dy = 0; dy < P13; ++dy) {
                float s0 = c1.v[dy * P13 + 0] * hv[0];
                float s1 = c1.v[dy * P13 + 1] * hv[1];
#pragma unroll
                for (int j = 2; j < P13; j += 2) s0 = fmaf(c1.v[dy * P13 + j], hv[j], s0);
#pragma unroll
                for (int j = 3; j < P13; j += 2) s1 = fmaf(c1.v[dy * P13 + j], hv[j], s1);
                U[wv][li][dy] = s0 + s1;
            }
            float s = 0.0f;
            const float* wp = &Wg[((size_t)img * IMGW + a) * IMGW + c];
#pragma unroll
            for (int dx = 0; dx < P13; ++dx) s += wp[dx * IMGW];
            vw[wv][li] = s;
        }
    }
    // same-wave LDS write->read: program order, no barrier needed
    float num = 0.0f;
#pragma unroll
    for (int dy = 0; dy < P13; ++dy) num += U[wv][lane + 12 - dy][dy];
    float den = 0.0f;
#pragma unroll
    for (int d = 0; d < P13; ++d) den += vw[wv][lane + d];
    const int ow = cb + lane;
    if (ow < OUTW)
        outg[((size_t)img * OUTW + a) * OUTW + ow] = num * __builtin_amdgcn_rcpf(den);
}

extern "C" void kernel_launch(void* const* d_in, const int* in_sizes, int n_in,
                              void* d_out, int out_size, void* d_ws, size_t ws_size,
                              hipStream_t stream)
{
    const float* x     = (const float*)d_in[0];
    const float* sigma = (const float*)d_in[1];
    float* out = (float*)d_out;

    C1mat c1;
    const double PI = 3.14159265358979323846;
    for (int xx = 0; xx < 13; ++xx)
        for (int k = 0; k < 13; ++k) {
            double Ci = (k == 0) ? (1.0 / sqrt(2.0)) : 1.0;
            c1.v[xx * 13 + k] =
                (float)(sqrt(2.0 / 13.0) * Ci * cos((2 * xx + 1) * k * PI / 26.0));
        }

    // ws: Hg (2*488*512*16 f32 = 31.98 MB) then Wg (2*512*512 f32 = 2 MB)
    float* Hg = (float*)d_ws;
    float* Wg = Hg + (size_t)2 * OUTW * HCOLS * HPITCH;

    dct2net_k2<<<dim3(32, NSEG, 2), 256, 0, stream>>>(x, sigma, Hg, Wg, c1);
    dct2net_k3<<<dim3(8, 122, 2), 256, 0, stream>>>(Hg, Wg, out, c1);
}